// Round 1
// baseline (246.899 us; speedup 1.0000x reference)
//
#include <hip/hip_runtime.h>
#include <hip/hip_bf16.h>

// WindowAttention3D: B=64 windows, N=512 tokens, H=6 heads, D=32, C=192.
// Plan:
//   k1 cpb_kernel:    tab6[3375][6]  = 16*sigmoid(MLP(coords)) * LOG2E
//   k2 bias_expand:   biasL[6][512][512] fp32 (gather via rel_pos_index)
//   k3 qkv_kernel:    bf16 MFMA GEMM x@W^T+b -> Q[b][h][n][d] (pre-scaled by
//                     1/sqrt(32)*LOG2E), K[b][h][n][d], Vt[b][h][d][n]
//   k4 attn_kernel:   swapped QK^T (mfma(K,Q)) so bias+mask load as f32x4
//                     directly into the MFMA C operand; exp2 without max
//                     subtraction (scores*log2e bounded ~32, fp32 sum safe);
//                     P -> LDS -> PV as O^T = Vt x P^T.

typedef __bf16 bf16x8 __attribute__((ext_vector_type(8)));
typedef __bf16 bf16x4v __attribute__((ext_vector_type(4)));
typedef float  f32x4  __attribute__((ext_vector_type(4)));

#define LOG2E 1.4426950408889634f

__device__ __forceinline__ bf16x8 cvt2_bf16x8(f32x4 a, f32x4 b) {
  bf16x8 r;
  r[0] = (__bf16)a[0]; r[1] = (__bf16)a[1]; r[2] = (__bf16)a[2]; r[3] = (__bf16)a[3];
  r[4] = (__bf16)b[0]; r[5] = (__bf16)b[1]; r[6] = (__bf16)b[2]; r[7] = (__bf16)b[3];
  return r;
}

// ---------------- k1: CPB MLP (3 -> 512 -> 6), fused 16*sigmoid*LOG2E ------
__global__ __launch_bounds__(256) void cpb_kernel(
    const float* __restrict__ table,   // (3375,3)
    const float* __restrict__ w1,      // (512,3)
    const float* __restrict__ b1,      // (512)
    const float* __restrict__ w2,      // (6,512)
    float* __restrict__ tab6)          // (3375,6)
{
  int p = blockIdx.x * 256 + threadIdx.x;
  if (p >= 3375) return;
  float c0 = table[p * 3 + 0], c1 = table[p * 3 + 1], c2 = table[p * 3 + 2];
  float acc[6] = {0.f, 0.f, 0.f, 0.f, 0.f, 0.f};
  for (int j = 0; j < 512; ++j) {
    float hv = w1[j * 3 + 0] * c0 + w1[j * 3 + 1] * c1 + w1[j * 3 + 2] * c2 + b1[j];
    hv = fmaxf(hv, 0.0f);
#pragma unroll
    for (int t = 0; t < 6; ++t) acc[t] += w2[t * 512 + j] * hv;
  }
#pragma unroll
  for (int t = 0; t < 6; ++t) {
    float s = 16.0f / (1.0f + expf(-acc[t]));
    tab6[p * 6 + t] = s * LOG2E;   // pre-scale by log2e for exp2-based softmax
  }
}

// ---------------- k2: expand bias table via rel_pos_index ------------------
__global__ __launch_bounds__(256) void bias_expand_kernel(
    const int* __restrict__ relidx,    // (512,512)
    const float* __restrict__ tab6,    // (3375,6)
    float* __restrict__ biasL)         // (6,512,512)
{
  int ij = blockIdx.x * 256 + threadIdx.x;   // 1024*256 == 262144 exactly
  int idx = relidx[ij];
#pragma unroll
  for (int t = 0; t < 6; ++t) biasL[(size_t)t * 262144 + ij] = tab6[idx * 6 + t];
}

// ---------------- k3: QKV projection GEMM (bf16 MFMA) ----------------------
// M=32768 rows (b*512+n), N=576 features, K=192. Wave tile: 32 rows x 192
// cols (3 nc-chunks of 64). A (x) fragments live in registers; B (w) from L2.
__global__ __launch_bounds__(256) void qkv_kernel(
    const float* __restrict__ x,       // (32768,192)
    const float* __restrict__ w,       // (576,192)
    const float* __restrict__ qb,      // (192)
    const float* __restrict__ vb,      // (192)
    __bf16* __restrict__ Qo,           // (64*6,512,32)
    __bf16* __restrict__ Ko,           // (64*6,512,32)
    __bf16* __restrict__ Vt)           // (64*6,32,512)
{
  const float CQ = 0.17677669529663687f * LOG2E;  // 1/sqrt(32) * log2e
  int lane = threadIdx.x & 63, wave = threadIdx.x >> 6;
  int g = lane >> 4, li = lane & 15;
  int wid = blockIdx.x * 4 + wave;     // 0..3071
  int rt = wid / 3, ncg = wid - rt * 3;
  int rowbase = rt * 32;

  // A fragments: 2 m-tiles x 6 k-steps, held for all 3 nc chunks
  bf16x8 a[2][6];
#pragma unroll
  for (int m = 0; m < 2; ++m)
#pragma unroll
    for (int k = 0; k < 6; ++k) {
      const float* xp = x + (size_t)(rowbase + m * 16 + li) * 192 + k * 32 + 8 * g;
      f32x4 x0 = *(const f32x4*)xp;
      f32x4 x1 = *(const f32x4*)(xp + 4);
      a[m][k] = cvt2_bf16x8(x0, x1);
    }

  for (int ncl = 0; ncl < 3; ++ncl) {
    int nc = ncg * 3 + ncl;            // output col chunk of 64
    f32x4 acc[2][4];
#pragma unroll
    for (int n = 0; n < 4; ++n) {
      int r = nc * 64 + n * 16 + li;
      float bb = 0.0f;
      if (r < 192) bb = qb[r];
      else if (r >= 384) bb = vb[r - 384];
      f32x4 v = {bb, bb, bb, bb};
      acc[0][n] = v; acc[1][n] = v;
    }
#pragma unroll
    for (int k = 0; k < 6; ++k) {
#pragma unroll
      for (int n = 0; n < 4; ++n) {
        const float* wp = w + (size_t)(nc * 64 + n * 16 + li) * 192 + k * 32 + 8 * g;
        f32x4 w0 = *(const f32x4*)wp;
        f32x4 w1v = *(const f32x4*)(wp + 4);
        bf16x8 bf = cvt2_bf16x8(w0, w1v);
        acc[0][n] = __builtin_amdgcn_mfma_f32_16x16x32_bf16(a[0][k], bf, acc[0][n], 0, 0, 0);
        acc[1][n] = __builtin_amdgcn_mfma_f32_16x16x32_bf16(a[1][k], bf, acc[1][n], 0, 0, 0);
      }
    }
    // Epilogue: route features to Q (scaled), K, Vt(transposed)
#pragma unroll
    for (int n = 0; n < 4; ++n) {
      int r = nc * 64 + n * 16 + li;   // feature id, branch uniform per (nc,n)
#pragma unroll
      for (int m = 0; m < 2; ++m) {
        int tok0 = rowbase + m * 16 + 4 * g;     // + t (4 consecutive tokens)
        int b = tok0 >> 9, nn = tok0 & 511;
        if (r < 192) {
          int h = r >> 5, d = r & 31;
          __bf16* dst = Qo + ((size_t)(b * 6 + h) * 512 + nn) * 32 + d;
#pragma unroll
          for (int t = 0; t < 4; ++t) dst[(size_t)t * 32] = (__bf16)(acc[m][n][t] * CQ);
        } else if (r < 384) {
          int rr = r - 192, h = rr >> 5, d = rr & 31;
          __bf16* dst = Ko + ((size_t)(b * 6 + h) * 512 + nn) * 32 + d;
#pragma unroll
          for (int t = 0; t < 4; ++t) dst[(size_t)t * 32] = (__bf16)acc[m][n][t];
        } else {
          int rr = r - 384, h = rr >> 5, d = rr & 31;
          bf16x4v pk;
#pragma unroll
          for (int t = 0; t < 4; ++t) pk[t] = (__bf16)acc[m][n][t];
          *(bf16x4v*)(Vt + ((size_t)(b * 6 + h) * 32 + d) * 512 + nn) = pk;
        }
      }
    }
  }
}

// ---------------- k4: attention ---------------------------------------------
// wg = (b, h, qtile of 128); 4 waves x 32 q-rows. Swapped QK^T: S^T = K x Q,
// D-frag: col = q-row (lane&15), rows = 4 consecutive keys -> bias+mask are
// f32x4 loads into the mfma C operand. exp2 with no max subtraction.
__global__ __launch_bounds__(256) void attn_kernel(
    const float* __restrict__ mask,    // (64,512,512) values {0,-1e4}
    const float* __restrict__ biasL,   // (6,512,512) pre-scaled by LOG2E
    const __bf16* __restrict__ Qw,     // (64*6,512,32), pre-scaled
    const __bf16* __restrict__ Kw,     // (64*6,512,32)
    const __bf16* __restrict__ Vt,     // (64*6,32,512)
    float* __restrict__ out)           // (64,6,512,32) fp32
{
  __shared__ __align__(16) __bf16 P_lds[4][32][72];  // per-wave [i][j], pad->72

  int wgid = blockIdx.x;
  int qt = wgid & 3, h = (wgid >> 2) % 6, b = wgid / 24;
  int lane = threadIdx.x & 63, wave = threadIdx.x >> 6;
  int g = lane >> 4, li = lane & 15;
  int qbase = qt * 128 + wave * 32;
  int bh = b * 6 + h;

  const __bf16* Qb = Qw + (size_t)bh * 512 * 32;
  const __bf16* Kb = Kw + (size_t)bh * 512 * 32;
  const __bf16* Vb = Vt + (size_t)bh * 32 * 512;
  const float* biasb = biasL + (size_t)h * 262144;
  const float* maskb = mask + (size_t)b * 262144;

  // Q fragments (B operand): col = q-row, k = d
  bf16x8 qfrag[2];
#pragma unroll
  for (int qf = 0; qf < 2; ++qf)
    qfrag[qf] = *(const bf16x8*)(Qb + (size_t)(qbase + qf * 16 + li) * 32 + 8 * g);

  f32x4 oacc[2][2] = {};        // [qf][df]: O^T frags (col=i, row=d)
  float l_part[2] = {0.f, 0.f}; // per-lane partial row sums

  for (int kb = 0; kb < 8; ++kb) {      // 64 keys per block
    int j64 = kb * 64;
    bf16x8 kfr[4];
#pragma unroll
    for (int kf = 0; kf < 4; ++kf)
      kfr[kf] = *(const bf16x8*)(Kb + (size_t)(j64 + kf * 16 + li) * 32 + 8 * g);
    bf16x8 vfr[2][2];
#pragma unroll
    for (int df = 0; df < 2; ++df)
#pragma unroll
      for (int c = 0; c < 2; ++c)
        vfr[df][c] = *(const bf16x8*)(Vb + (size_t)(df * 16 + li) * 512 + j64 + c * 32 + 8 * g);

    // S^T = K x Q with C = bias*log2e + mask; then P = exp2(S^T)
#pragma unroll
    for (int kf = 0; kf < 4; ++kf) {
      int j0 = j64 + kf * 16 + 4 * g;   // 4 consecutive keys per lane (regs)
#pragma unroll
      for (int qf = 0; qf < 2; ++qf) {
        int i = qbase + qf * 16 + li;
        f32x4 cinit = *(const f32x4*)(biasb + (size_t)i * 512 + j0);
        f32x4 mv    = *(const f32x4*)(maskb + (size_t)i * 512 + j0);
        cinit += mv;  // -1e4 keeps exp2 at exactly 0 for masked entries
        f32x4 s = __builtin_amdgcn_mfma_f32_16x16x32_bf16(kfr[kf], qfrag[qf], cinit, 0, 0, 0);
        float p0 = exp2f(s[0]);
        float p1 = exp2f(s[1]);
        float p2 = exp2f(s[2]);
        float p3 = exp2f(s[3]);
        l_part[qf] += (p0 + p1) + (p2 + p3);
        bf16x4v pk;
        pk[0] = (__bf16)p0; pk[1] = (__bf16)p1; pk[2] = (__bf16)p2; pk[3] = (__bf16)p3;
        *(bf16x4v*)&P_lds[wave][qf * 16 + li][kf * 16 + 4 * g] = pk;
      }
    }
    // PV: O^T += Vt x P^T   (A row = d, k = j; B col = i, k = j)
#pragma unroll
    for (int c = 0; c < 2; ++c) {
      bf16x8 pf0 = *(const bf16x8*)&P_lds[wave][li][c * 32 + 8 * g];
      bf16x8 pf1 = *(const bf16x8*)&P_lds[wave][16 + li][c * 32 + 8 * g];
#pragma unroll
      for (int df = 0; df < 2; ++df) {
        oacc[0][df] = __builtin_amdgcn_mfma_f32_16x16x32_bf16(vfr[df][c], pf0, oacc[0][df], 0, 0, 0);
        oacc[1][df] = __builtin_amdgcn_mfma_f32_16x16x32_bf16(vfr[df][c], pf1, oacc[1][df], 0, 0, 0);
      }
    }
  }

  // Epilogue: finish row sums across the 4 lane-groups, normalize, store.
#pragma unroll
  for (int qf = 0; qf < 2; ++qf) {
    float l = l_part[qf];
    l += __shfl_xor(l, 16);
    l += __shfl_xor(l, 32);
    float linv = 1.0f / l;
#pragma unroll
    for (int df = 0; df < 2; ++df) {
      float* op = out + ((size_t)bh * 512 + qbase + qf * 16 + li) * 32 + df * 16 + 4 * g;
#pragma unroll
      for (int t = 0; t < 4; ++t) op[t] = oacc[qf][df][t] * linv;
    }
  }
}

extern "C" void kernel_launch(void* const* d_in, const int* in_sizes, int n_in,
                              void* d_out, int out_size, void* d_ws, size_t ws_size,
                              hipStream_t stream) {
  const float* x    = (const float*)d_in[0];
  const float* mask = (const float*)d_in[1];
  const float* wqkv = (const float*)d_in[2];
  const float* qb   = (const float*)d_in[3];
  const float* vb   = (const float*)d_in[4];
  const float* w1   = (const float*)d_in[5];
  const float* b1   = (const float*)d_in[6];
  const float* w2   = (const float*)d_in[7];
  const float* tbl  = (const float*)d_in[8];
  const int*   ridx = (const int*)d_in[9];
  float* out = (float*)d_out;

  char* ws = (char*)d_ws;
  float* tab6  = (float*)(ws);                          // 81000 B (pad 81920)
  float* biasL = (float*)(ws + 81920);                  // 6291456 B
  __bf16* Q    = (__bf16*)(ws + 81920 + 6291456);       // 12582912 B
  __bf16* K    = Q + (size_t)64 * 6 * 512 * 32;         // 12582912 B
  __bf16* Vt   = K + (size_t)64 * 6 * 512 * 32;         // 12582912 B
  // total ws use: ~44.1 MB

  cpb_kernel<<<14, 256, 0, stream>>>(tbl, w1, b1, w2, tab6);
  bias_expand_kernel<<<1024, 256, 0, stream>>>(ridx, tab6, biasL);
  qkv_kernel<<<768, 256, 0, stream>>>(x, wqkv, qb, vb, Q, K, Vt);
  attn_kernel<<<1536, 256, 0, stream>>>(mask, biasL, Q, K, Vt, out);
}

// Round 2
// 228.993 us; speedup vs baseline: 1.0782x; 1.0782x over previous
//
#include <hip/hip_runtime.h>
#include <hip/hip_bf16.h>

// WindowAttention3D: B=64 windows, N=512 tokens, H=6 heads, D=32, C=192.
//   k0 wconv:        w_qkv fp32 -> bf16 (221 KB, L2-resident everywhere)
//   k1 cpb_kernel:   tab6[3375][6] = 16*sigmoid(MLP(coords)) * LOG2E  (fp32)
//   k2 bias_expand:  biasH[6][512][512] fp16 (gather via rel_pos_index)
//   k2b maskbits:    bits[b][jw][i] uint64, bit=unmasked  (67 MB -> 2 MB)
//   k3 qkv_kernel:   bf16 MFMA GEMM -> Q (pre-scaled 1/sqrt(32)*LOG2E), K,
//                    Vt (transposed)
//   k4 attn_kernel:  swapped QK^T (mfma(K,Q)), bias f16 -> fp32 C-operand,
//                    exp2 (no max subtraction; bounded), mask via bit-select,
//                    P -> LDS -> PV as O^T = Vt x P^T. XCD-chunked swizzle.

typedef __bf16 bf16x8 __attribute__((ext_vector_type(8)));
typedef __bf16 bf16x4v __attribute__((ext_vector_type(4)));
typedef float  f32x4  __attribute__((ext_vector_type(4)));
typedef _Float16 f16x4 __attribute__((ext_vector_type(4)));
typedef unsigned long long u64;

#define LOG2E 1.4426950408889634f

__device__ __forceinline__ bf16x8 cvt2_bf16x8(f32x4 a, f32x4 b) {
  bf16x8 r;
  r[0] = (__bf16)a[0]; r[1] = (__bf16)a[1]; r[2] = (__bf16)a[2]; r[3] = (__bf16)a[3];
  r[4] = (__bf16)b[0]; r[5] = (__bf16)b[1]; r[6] = (__bf16)b[2]; r[7] = (__bf16)b[3];
  return r;
}

// ---------------- k0: w_qkv fp32 -> bf16 ------------------------------------
__global__ __launch_bounds__(256) void wconv_kernel(
    const float* __restrict__ w, __bf16* __restrict__ wbf) {
  int t = blockIdx.x * 256 + threadIdx.x;       // 27648 threads x 4 elems
  f32x4 v = *(const f32x4*)(w + (size_t)t * 4);
  bf16x4v o;
  o[0] = (__bf16)v[0]; o[1] = (__bf16)v[1]; o[2] = (__bf16)v[2]; o[3] = (__bf16)v[3];
  *(bf16x4v*)(wbf + (size_t)t * 4) = o;
}

// ---------------- k1: CPB MLP (3 -> 512 -> 6), fused 16*sigmoid*LOG2E ------
__global__ __launch_bounds__(256) void cpb_kernel(
    const float* __restrict__ table,   // (3375,3)
    const float* __restrict__ w1,      // (512,3)
    const float* __restrict__ b1,      // (512)
    const float* __restrict__ w2,      // (6,512)
    float* __restrict__ tab6)          // (3375,6)
{
  int p = blockIdx.x * 256 + threadIdx.x;
  if (p >= 3375) return;
  float c0 = table[p * 3 + 0], c1 = table[p * 3 + 1], c2 = table[p * 3 + 2];
  float acc[6] = {0.f, 0.f, 0.f, 0.f, 0.f, 0.f};
  for (int j = 0; j < 512; ++j) {
    float hv = w1[j * 3 + 0] * c0 + w1[j * 3 + 1] * c1 + w1[j * 3 + 2] * c2 + b1[j];
    hv = fmaxf(hv, 0.0f);
#pragma unroll
    for (int t = 0; t < 6; ++t) acc[t] += w2[t * 512 + j] * hv;
  }
#pragma unroll
  for (int t = 0; t < 6; ++t) {
    float s = 16.0f / (1.0f + expf(-acc[t]));
    tab6[p * 6 + t] = s * LOG2E;   // pre-scale by log2e for exp2-based softmax
  }
}

// ---------------- k2: expand bias table via rel_pos_index -> fp16 -----------
__global__ __launch_bounds__(256) void bias_expand_kernel(
    const int* __restrict__ relidx,    // (512,512)
    const float* __restrict__ tab6,    // (3375,6)
    _Float16* __restrict__ biasH)      // (6,512,512) fp16, pre-scaled LOG2E
{
  int ij = blockIdx.x * 256 + threadIdx.x;   // 1024*256 == 262144 exactly
  int idx = relidx[ij];
#pragma unroll
  for (int t = 0; t < 6; ++t)
    biasH[(size_t)t * 262144 + ij] = (_Float16)tab6[idx * 6 + t];
}

// ---------------- k2b: mask -> bitmask (bit=1 means unmasked) ---------------
// layout bits[b][jw][i] (jw = j/64) so attn's 16 row-lanes read contiguous 8B.
__global__ __launch_bounds__(256) void maskbits_kernel(
    const float* __restrict__ m, u64* __restrict__ bits) {
  size_t gid = (size_t)blockIdx.x * 256 + threadIdx.x;  // 16,777,216 total
  int word = (int)(gid >> 6);
  int lane = threadIdx.x & 63;
  float v = m[gid];                       // fully coalesced
  u64 bal = __ballot(v == 0.0f);
  if (lane == 0) {
    int b = word >> 12, i = (word >> 3) & 511, jw = word & 7;
    bits[(((size_t)b * 8 + jw) << 9) + i] = bal;
  }
}

// ---------------- k3: QKV projection GEMM (bf16 MFMA) ----------------------
__global__ __launch_bounds__(256) void qkv_kernel(
    const float* __restrict__ x,       // (32768,192) fp32
    const __bf16* __restrict__ wbf,    // (576,192) bf16
    const float* __restrict__ qb,      // (192)
    const float* __restrict__ vb,      // (192)
    __bf16* __restrict__ Qo,           // (64*6,512,32)
    __bf16* __restrict__ Ko,           // (64*6,512,32)
    __bf16* __restrict__ Vt)           // (64*6,32,512)
{
  const float CQ = 0.17677669529663687f * LOG2E;  // 1/sqrt(32) * log2e
  int lane = threadIdx.x & 63, wave = threadIdx.x >> 6;
  int g = lane >> 4, li = lane & 15;
  int wid = blockIdx.x * 4 + wave;     // 0..3071
  int rt = wid / 3, ncg = wid - rt * 3;
  int rowbase = rt * 32;

  // A fragments: 2 m-tiles x 6 k-steps, held for all 3 nc chunks
  bf16x8 a[2][6];
#pragma unroll
  for (int m = 0; m < 2; ++m)
#pragma unroll
    for (int k = 0; k < 6; ++k) {
      const float* xp = x + (size_t)(rowbase + m * 16 + li) * 192 + k * 32 + 8 * g;
      f32x4 x0 = *(const f32x4*)xp;
      f32x4 x1 = *(const f32x4*)(xp + 4);
      a[m][k] = cvt2_bf16x8(x0, x1);
    }

  for (int ncl = 0; ncl < 3; ++ncl) {
    int nc = ncg * 3 + ncl;            // output col chunk of 64
    f32x4 acc[2][4];
#pragma unroll
    for (int n = 0; n < 4; ++n) {
      int r = nc * 64 + n * 16 + li;
      float bb = 0.0f;
      if (r < 192) bb = qb[r];
      else if (r >= 384) bb = vb[r - 384];
      f32x4 v = {bb, bb, bb, bb};
      acc[0][n] = v; acc[1][n] = v;
    }
#pragma unroll
    for (int k = 0; k < 6; ++k) {
#pragma unroll
      for (int n = 0; n < 4; ++n) {
        bf16x8 bf = *(const bf16x8*)(wbf + (size_t)(nc * 64 + n * 16 + li) * 192 + k * 32 + 8 * g);
        acc[0][n] = __builtin_amdgcn_mfma_f32_16x16x32_bf16(a[0][k], bf, acc[0][n], 0, 0, 0);
        acc[1][n] = __builtin_amdgcn_mfma_f32_16x16x32_bf16(a[1][k], bf, acc[1][n], 0, 0, 0);
      }
    }
    // Epilogue: route features to Q (scaled), K, Vt(transposed)
#pragma unroll
    for (int n = 0; n < 4; ++n) {
      int r = nc * 64 + n * 16 + li;   // feature id, branch uniform per (nc,n)
#pragma unroll
      for (int m = 0; m < 2; ++m) {
        int tok0 = rowbase + m * 16 + 4 * g;     // + t (4 consecutive tokens)
        int b = tok0 >> 9, nn = tok0 & 511;
        if (r < 192) {
          int h = r >> 5, d = r & 31;
          __bf16* dst = Qo + ((size_t)(b * 6 + h) * 512 + nn) * 32 + d;
#pragma unroll
          for (int t = 0; t < 4; ++t) dst[(size_t)t * 32] = (__bf16)(acc[m][n][t] * CQ);
        } else if (r < 384) {
          int rr = r - 192, h = rr >> 5, d = rr & 31;
          __bf16* dst = Ko + ((size_t)(b * 6 + h) * 512 + nn) * 32 + d;
#pragma unroll
          for (int t = 0; t < 4; ++t) dst[(size_t)t * 32] = (__bf16)acc[m][n][t];
        } else {
          int rr = r - 384, h = rr >> 5, d = rr & 31;
          bf16x4v pk;
#pragma unroll
          for (int t = 0; t < 4; ++t) pk[t] = (__bf16)acc[m][n][t];
          *(bf16x4v*)(Vt + ((size_t)(b * 6 + h) * 32 + d) * 512 + nn) = pk;
        }
      }
    }
  }
}

// ---------------- k4: attention ---------------------------------------------
__global__ __launch_bounds__(256) void attn_kernel(
    const u64* __restrict__ bits,      // (64,8,512) unmasked-bit words
    const _Float16* __restrict__ biasH,// (6,512,512) fp16, pre-scaled LOG2E
    const __bf16* __restrict__ Qw,     // (64*6,512,32), pre-scaled
    const __bf16* __restrict__ Kw,     // (64*6,512,32)
    const __bf16* __restrict__ Vt,     // (64*6,32,512)
    float* __restrict__ out)           // (64,6,512,32) fp32
{
  __shared__ __align__(16) __bf16 P_lds[4][32][72];  // per-wave [i][j], pad->72

  // XCD-chunked bijective swizzle: hw round-robins XCDs (hw%8), so logical
  // ids [x*192,(x+1)*192) = windows [x*8, x*8+8) land together on one XCD.
  int hw = blockIdx.x;
  int wgid = (hw & 7) * 192 + (hw >> 3);
  int qt = wgid & 3, h = (wgid >> 2) % 6, b = wgid / 24;
  int lane = threadIdx.x & 63, wave = threadIdx.x >> 6;
  int g = lane >> 4, li = lane & 15;
  int qbase = qt * 128 + wave * 32;
  int bh = b * 6 + h;

  const __bf16* Qb = Qw + (size_t)bh * 512 * 32;
  const __bf16* Kb = Kw + (size_t)bh * 512 * 32;
  const __bf16* Vb = Vt + (size_t)bh * 32 * 512;
  const _Float16* biasb = biasH + (size_t)h * 262144;
  const u64* bitsb = bits + (size_t)b * 8 * 512;

  // Q fragments (B operand): col = q-row, k = d
  bf16x8 qfrag[2];
#pragma unroll
  for (int qf = 0; qf < 2; ++qf)
    qfrag[qf] = *(const bf16x8*)(Qb + (size_t)(qbase + qf * 16 + li) * 32 + 8 * g);

  f32x4 oacc[2][2] = {};        // [qf][df]: O^T frags (col=i, row=d)
  float l_part[2] = {0.f, 0.f}; // per-lane partial row sums

  for (int kb = 0; kb < 8; ++kb) {      // 64 keys per block
    int j64 = kb * 64;
    bf16x8 kfr[4];
#pragma unroll
    for (int kf = 0; kf < 4; ++kf)
      kfr[kf] = *(const bf16x8*)(Kb + (size_t)(j64 + kf * 16 + li) * 32 + 8 * g);
    bf16x8 vfr[2][2];
#pragma unroll
    for (int df = 0; df < 2; ++df)
#pragma unroll
      for (int c = 0; c < 2; ++c)
        vfr[df][c] = *(const bf16x8*)(Vb + (size_t)(df * 16 + li) * 512 + j64 + c * 32 + 8 * g);
    u64 mb[2];
#pragma unroll
    for (int qf = 0; qf < 2; ++qf)
      mb[qf] = bitsb[((size_t)kb << 9) + qbase + qf * 16 + li];

    // S^T = K x Q with C = bias*log2e; P = exp2(S^T), masked -> 0 via bits
#pragma unroll
    for (int kf = 0; kf < 4; ++kf) {
      int j0 = j64 + kf * 16 + 4 * g;   // 4 consecutive keys per lane
#pragma unroll
      for (int qf = 0; qf < 2; ++qf) {
        int i = qbase + qf * 16 + li;
        f16x4 hv = *(const f16x4*)(biasb + (size_t)i * 512 + j0);
        f32x4 cinit = {(float)hv[0], (float)hv[1], (float)hv[2], (float)hv[3]};
        f32x4 s = __builtin_amdgcn_mfma_f32_16x16x32_bf16(kfr[kf], qfrag[qf], cinit, 0, 0, 0);
        unsigned nib = (unsigned)(mb[qf] >> (kf * 16 + 4 * g)) & 15u;
        float p0 = (nib & 1u) ? __builtin_amdgcn_exp2f(s[0]) : 0.0f;
        float p1 = (nib & 2u) ? __builtin_amdgcn_exp2f(s[1]) : 0.0f;
        float p2 = (nib & 4u) ? __builtin_amdgcn_exp2f(s[2]) : 0.0f;
        float p3 = (nib & 8u) ? __builtin_amdgcn_exp2f(s[3]) : 0.0f;
        l_part[qf] += (p0 + p1) + (p2 + p3);
        bf16x4v pk;
        pk[0] = (__bf16)p0; pk[1] = (__bf16)p1; pk[2] = (__bf16)p2; pk[3] = (__bf16)p3;
        *(bf16x4v*)&P_lds[wave][qf * 16 + li][kf * 16 + 4 * g] = pk;
      }
    }
    // PV: O^T += Vt x P^T   (A row = d, k = j; B col = i, k = j)
#pragma unroll
    for (int c = 0; c < 2; ++c) {
      bf16x8 pf0 = *(const bf16x8*)&P_lds[wave][li][c * 32 + 8 * g];
      bf16x8 pf1 = *(const bf16x8*)&P_lds[wave][16 + li][c * 32 + 8 * g];
#pragma unroll
      for (int df = 0; df < 2; ++df) {
        oacc[0][df] = __builtin_amdgcn_mfma_f32_16x16x32_bf16(vfr[df][c], pf0, oacc[0][df], 0, 0, 0);
        oacc[1][df] = __builtin_amdgcn_mfma_f32_16x16x32_bf16(vfr[df][c], pf1, oacc[1][df], 0, 0, 0);
      }
    }
  }

  // Epilogue: finish row sums across lane-groups, normalize, store.
#pragma unroll
  for (int qf = 0; qf < 2; ++qf) {
    float l = l_part[qf];
    l += __shfl_xor(l, 16);
    l += __shfl_xor(l, 32);
    float linv = 1.0f / l;
#pragma unroll
    for (int df = 0; df < 2; ++df) {
      float* op = out + ((size_t)bh * 512 + qbase + qf * 16 + li) * 32 + df * 16 + 4 * g;
#pragma unroll
      for (int t = 0; t < 4; ++t) op[t] = oacc[qf][df][t] * linv;
    }
  }
}

extern "C" void kernel_launch(void* const* d_in, const int* in_sizes, int n_in,
                              void* d_out, int out_size, void* d_ws, size_t ws_size,
                              hipStream_t stream) {
  const float* x    = (const float*)d_in[0];
  const float* mask = (const float*)d_in[1];
  const float* wqkv = (const float*)d_in[2];
  const float* qb   = (const float*)d_in[3];
  const float* vb   = (const float*)d_in[4];
  const float* w1   = (const float*)d_in[5];
  const float* b1   = (const float*)d_in[6];
  const float* w2   = (const float*)d_in[7];
  const float* tbl  = (const float*)d_in[8];
  const int*   ridx = (const int*)d_in[9];
  float* out = (float*)d_out;

  char* ws = (char*)d_ws;
  float*    tab6  = (float*)(ws);                         //    81,920 B
  _Float16* biasH = (_Float16*)(ws + 81920);              // 3,145,728 B
  u64*      bits  = (u64*)(ws + 81920 + 3145728);         // 2,097,152 B
  __bf16*   wbf   = (__bf16*)(ws + 81920 + 3145728 + 2097152);  // 221,184 -> pad 262,144
  __bf16*   Q     = (__bf16*)(ws + 81920 + 3145728 + 2097152 + 262144);
  __bf16*   K     = Q + (size_t)64 * 6 * 512 * 32;        // 12,582,912 B each
  __bf16*   Vt    = K + (size_t)64 * 6 * 512 * 32;
  // total ws use: ~43.3 MB

  wconv_kernel<<<108, 256, 0, stream>>>(wqkv, wbf);
  cpb_kernel<<<14, 256, 0, stream>>>(tbl, w1, b1, w2, tab6);
  bias_expand_kernel<<<1024, 256, 0, stream>>>(ridx, tab6, biasH);
  maskbits_kernel<<<65536, 256, 0, stream>>>(mask, bits);
  qkv_kernel<<<768, 256, 0, stream>>>(x, wbf, qb, vb, Q, K, Vt);
  attn_kernel<<<1536, 256, 0, stream>>>(bits, biasH, Q, K, Vt, out);
}

// Round 3
// 200.395 us; speedup vs baseline: 1.2321x; 1.1427x over previous
//
#include <hip/hip_runtime.h>
#include <hip/hip_bf16.h>

// WindowAttention3D: B=64 windows, N=512 tokens, H=6 heads, D=32, C=192.
//   k0 wconv:        w_qkv fp32 -> bf16
//   k1 cpb_kernel:   tab6[3375][6] = 16*sigmoid(MLP(coords)) * LOG2E (LDS wts)
//   k2 bias_expand:  biasH[6][512][512] fp16 (gather via rel_pos_index)
//   k2b maskbits:    bits[b][jw][i] uint64, bit=unmasked (67 MB -> 2 MB)
//   k3 qkv_kernel:   bf16 MFMA GEMM -> Q (pre-scaled 1/sqrt(32)*LOG2E), K,
//                    Vt; Q/K epilogue via LDS transpose -> coalesced stores
//   k4 attn_kernel:  swapped QK^T (mfma(K,Q)); P relayout for PV entirely
//                    in-register via permlane32_swap+permlane16_swap (no LDS,
//                    no barriers). exp2, bit-mask select, XCD-chunked swizzle.

typedef __bf16 bf16x8 __attribute__((ext_vector_type(8)));
typedef __bf16 bf16x4v __attribute__((ext_vector_type(4)));
typedef float  f32x4  __attribute__((ext_vector_type(4)));
typedef _Float16 f16x4 __attribute__((ext_vector_type(4)));
typedef unsigned uint2v __attribute__((ext_vector_type(2)));
typedef unsigned long long u64;

#define LOG2E 1.4426950408889634f

__device__ __forceinline__ bf16x8 cvt2_bf16x8(f32x4 a, f32x4 b) {
  bf16x8 r;
  r[0] = (__bf16)a[0]; r[1] = (__bf16)a[1]; r[2] = (__bf16)a[2]; r[3] = (__bf16)a[3];
  r[4] = (__bf16)b[0]; r[5] = (__bf16)b[1]; r[6] = (__bf16)b[2]; r[7] = (__bf16)b[3];
  return r;
}

__device__ __forceinline__ unsigned pack2bf(float a, float b) {
  unsigned short ua = __builtin_bit_cast(unsigned short, (__bf16)a);
  unsigned short ub = __builtin_bit_cast(unsigned short, (__bf16)b);
  return (unsigned)ua | ((unsigned)ub << 16);
}

__device__ __forceinline__ bf16x8 frag_from_words(unsigned w0, unsigned w1,
                                                  unsigned w2, unsigned w3) {
  union { unsigned u[4]; bf16x8 v; } f;
  f.u[0] = w0; f.u[1] = w1; f.u[2] = w2; f.u[3] = w3;
  return f.v;
}

// ---------------- k0: w_qkv fp32 -> bf16 ------------------------------------
__global__ __launch_bounds__(256) void wconv_kernel(
    const float* __restrict__ w, __bf16* __restrict__ wbf) {
  int t = blockIdx.x * 256 + threadIdx.x;       // 27648 threads x 4 elems
  f32x4 v = *(const f32x4*)(w + (size_t)t * 4);
  bf16x4v o;
  o[0] = (__bf16)v[0]; o[1] = (__bf16)v[1]; o[2] = (__bf16)v[2]; o[3] = (__bf16)v[3];
  *(bf16x4v*)(wbf + (size_t)t * 4) = o;
}

// ---------------- k1: CPB MLP (3 -> 512 -> 6), weights in LDS ---------------
__global__ __launch_bounds__(256) void cpb_kernel(
    const float* __restrict__ table,   // (3375,3)
    const float* __restrict__ w1,      // (512,3)
    const float* __restrict__ b1,      // (512)
    const float* __restrict__ w2,      // (6,512)
    float* __restrict__ tab6)          // (3375,6)
{
  __shared__ float sw1[1536], sb1[512], sw2[3072];
  for (int t = threadIdx.x; t < 1536; t += 256) sw1[t] = w1[t];
  for (int t = threadIdx.x; t < 512; t += 256) sb1[t] = b1[t];
  for (int t = threadIdx.x; t < 3072; t += 256) sw2[t] = w2[t];
  __syncthreads();
  int p = blockIdx.x * 256 + threadIdx.x;
  if (p >= 3375) return;
  float c0 = table[p * 3 + 0], c1 = table[p * 3 + 1], c2 = table[p * 3 + 2];
  float acc[6] = {0.f, 0.f, 0.f, 0.f, 0.f, 0.f};
#pragma unroll 4
  for (int j = 0; j < 512; ++j) {
    float hv = sw1[j * 3 + 0] * c0 + sw1[j * 3 + 1] * c1 + sw1[j * 3 + 2] * c2 + sb1[j];
    hv = fmaxf(hv, 0.0f);
#pragma unroll
    for (int t = 0; t < 6; ++t) acc[t] += sw2[t * 512 + j] * hv;
  }
#pragma unroll
  for (int t = 0; t < 6; ++t) {
    float s = 16.0f / (1.0f + expf(-acc[t]));
    tab6[p * 6 + t] = s * LOG2E;   // pre-scale by log2e for exp2-based softmax
  }
}

// ---------------- k2: expand bias table via rel_pos_index -> fp16 -----------
__global__ __launch_bounds__(256) void bias_expand_kernel(
    const int* __restrict__ relidx,    // (512,512)
    const float* __restrict__ tab6,    // (3375,6)
    _Float16* __restrict__ biasH)      // (6,512,512) fp16, pre-scaled LOG2E
{
  int ij = blockIdx.x * 256 + threadIdx.x;   // 1024*256 == 262144 exactly
  int idx = relidx[ij];
#pragma unroll
  for (int t = 0; t < 6; ++t)
    biasH[(size_t)t * 262144 + ij] = (_Float16)tab6[idx * 6 + t];
}

// ---------------- k2b: mask -> bitmask (bit=1 means unmasked) ---------------
__global__ __launch_bounds__(256) void maskbits_kernel(
    const float* __restrict__ m, u64* __restrict__ bits) {
  for (size_t gid = (size_t)blockIdx.x * 256 + threadIdx.x; gid < 16777216ull;
       gid += (size_t)8192 * 256) {
    int word = (int)(gid >> 6);
    int lane = threadIdx.x & 63;
    float v = m[gid];                     // fully coalesced
    u64 bal = __ballot(v == 0.0f);
    if (lane == 0) {
      int b = word >> 12, i = (word >> 3) & 511, jw = word & 7;
      bits[(((size_t)b * 8 + jw) << 9) + i] = bal;
    }
  }
}

// ---------------- k3: QKV projection GEMM (bf16 MFMA) ----------------------
// 1024 blocks x 3 waves; block = 32 tokens (shared x via L1), wave = region
// (0:Q scaled, 1:K, 2:V). Q/K epilogue transposes via per-wave LDS tile so
// global stores are 16B coalesced. V stores bf16x4 direct (transposed layout).
__global__ __launch_bounds__(192) void qkv_kernel(
    const float* __restrict__ x,       // (32768,192) fp32
    const __bf16* __restrict__ wbf,    // (576,192) bf16
    const float* __restrict__ qb,      // (192)
    const float* __restrict__ vb,      // (192)
    __bf16* __restrict__ Qo,           // (64*6,512,32)
    __bf16* __restrict__ Ko,           // (64*6,512,32)
    __bf16* __restrict__ Vt)           // (64*6,32,512)
{
  const float CQ = 0.17677669529663687f * LOG2E;  // 1/sqrt(32) * log2e
  __shared__ __bf16 tile[2][32][72];   // waves 0,1 transpose staging (9216 B)
  int lane = threadIdx.x & 63, wave = threadIdx.x >> 6;
  int g = lane >> 4, li = lane & 15;
  int rowbase = blockIdx.x * 32;
  int b = rowbase >> 9, nbase = rowbase & 511;

  // A fragments: 2 m-tiles x 6 k-steps (same for all 3 waves -> L1 shared)
  bf16x8 a[2][6];
#pragma unroll
  for (int m = 0; m < 2; ++m)
#pragma unroll
    for (int k = 0; k < 6; ++k) {
      const float* xp = x + (size_t)(rowbase + m * 16 + li) * 192 + k * 32 + 8 * g;
      f32x4 x0 = *(const f32x4*)xp;
      f32x4 x1 = *(const f32x4*)(xp + 4);
      a[m][k] = cvt2_bf16x8(x0, x1);
    }

  for (int ncl = 0; ncl < 3; ++ncl) {
    int nc = wave * 3 + ncl;           // output col chunk of 64 (region=wave)
    f32x4 acc[2][4];
#pragma unroll
    for (int n = 0; n < 4; ++n) {
      int r = nc * 64 + n * 16 + li;
      float bb = 0.0f;
      if (r < 192) bb = qb[r];
      else if (r >= 384) bb = vb[r - 384];
      f32x4 v = {bb, bb, bb, bb};
      acc[0][n] = v; acc[1][n] = v;
    }
#pragma unroll
    for (int k = 0; k < 6; ++k) {
#pragma unroll
      for (int n = 0; n < 4; ++n) {
        bf16x8 bf = *(const bf16x8*)(wbf + (size_t)(nc * 64 + n * 16 + li) * 192 + k * 32 + 8 * g);
        acc[0][n] = __builtin_amdgcn_mfma_f32_16x16x32_bf16(a[0][k], bf, acc[0][n], 0, 0, 0);
        acc[1][n] = __builtin_amdgcn_mfma_f32_16x16x32_bf16(a[1][k], bf, acc[1][n], 0, 0, 0);
      }
    }
    // ---- epilogue ----
    if (wave < 2) {
      float scale = (wave == 0) ? CQ : 1.0f;
#pragma unroll
      for (int n = 0; n < 4; ++n)
#pragma unroll
        for (int m = 0; m < 2; ++m)
#pragma unroll
          for (int t = 0; t < 4; ++t)
            tile[wave][m * 16 + 4 * g + t][n * 16 + li] = (__bf16)(acc[m][n][t] * scale);
    }
    __syncthreads();
    if (wave < 2) {
      int tok = lane & 31, hh = lane >> 5;
      int h = (nc * 2 + hh) % 6;
      __bf16* base = (wave == 0) ? Qo : Ko;
      __bf16* dst = base + ((size_t)(b * 6 + h) * 512 + nbase + tok) * 32;
#pragma unroll
      for (int kq = 0; kq < 4; ++kq)
        *(bf16x8*)(dst + kq * 8) = *(const bf16x8*)&tile[wave][tok][hh * 32 + kq * 8];
    } else {
#pragma unroll
      for (int n = 0; n < 4; ++n) {
        int rr = nc * 64 + n * 16 + li - 384, h = rr >> 5, d = rr & 31;
#pragma unroll
        for (int m = 0; m < 2; ++m) {
          int nn = nbase + m * 16 + 4 * g;
          bf16x4v pk;
#pragma unroll
          for (int t = 0; t < 4; ++t) pk[t] = (__bf16)acc[m][n][t];
          *(bf16x4v*)(Vt + ((size_t)(b * 6 + h) * 32 + d) * 512 + nn) = pk;
        }
      }
    }
    __syncthreads();
  }
}

// ---------------- k4: attention (no LDS, register-only P) -------------------
__global__ __launch_bounds__(256) void attn_kernel(
    const u64* __restrict__ bits,      // (64,8,512) unmasked-bit words
    const _Float16* __restrict__ biasH,// (6,512,512) fp16, pre-scaled LOG2E
    const __bf16* __restrict__ Qw,     // (64*6,512,32), pre-scaled
    const __bf16* __restrict__ Kw,     // (64*6,512,32)
    const __bf16* __restrict__ Vt,     // (64*6,32,512)
    float* __restrict__ out)           // (64,6,512,32) fp32
{
  // XCD-chunked bijective swizzle (1536 % 8 == 0)
  int hw = blockIdx.x;
  int wgid = (hw & 7) * 192 + (hw >> 3);
  int qt = wgid & 3, h = (wgid >> 2) % 6, b = wgid / 24;
  int lane = threadIdx.x & 63, wave = threadIdx.x >> 6;
  int g = lane >> 4, li = lane & 15;
  int qbase = qt * 128 + wave * 32;
  int bh = b * 6 + h;

  const __bf16* Qb = Qw + (size_t)bh * 16384;
  const __bf16* Kb = Kw + (size_t)bh * 16384;
  const __bf16* Vb = Vt + (size_t)bh * 16384;
  const _Float16* biasb = biasH + (size_t)h * 262144;
  const u64* bitsb = bits + (size_t)b * 4096;

  bf16x8 qfrag[2];
#pragma unroll
  for (int qf = 0; qf < 2; ++qf)
    qfrag[qf] = *(const bf16x8*)(Qb + (size_t)(qbase + qf * 16 + li) * 32 + 8 * g);

  f32x4 oacc[2][2] = {};        // [qf][df]: O^T frags (col=i, row=d)
  float l_part[2] = {0.f, 0.f};

  for (int kb = 0; kb < 8; ++kb) {      // 64 keys per block
    int j64 = kb * 64;
    u64 mb[2];
#pragma unroll
    for (int qf = 0; qf < 2; ++qf)
      mb[qf] = bitsb[((size_t)kb << 9) + qbase + qf * 16 + li];

#pragma unroll
    for (int c = 0; c < 2; ++c) {       // 32 keys per c-chunk
      int j32 = j64 + c * 32;
      bf16x8 kfr[2];
      kfr[0] = *(const bf16x8*)(Kb + (size_t)(j32 + li) * 32 + 8 * g);
      kfr[1] = *(const bf16x8*)(Kb + (size_t)(j32 + 16 + li) * 32 + 8 * g);
      bf16x8 vfr[2];
      vfr[0] = *(const bf16x8*)(Vb + (size_t)(li) * 512 + j32 + 8 * g);
      vfr[1] = *(const bf16x8*)(Vb + (size_t)(16 + li) * 512 + j32 + 8 * g);

      unsigned lo[2][2], hi[2][2];      // [qf][kfl]
#pragma unroll
      for (int kfl = 0; kfl < 2; ++kfl) {
        int kf = c * 2 + kfl;
        int j0 = j64 + kf * 16 + 4 * g; // 4 consecutive keys per lane
#pragma unroll
        for (int qf = 0; qf < 2; ++qf) {
          int i = qbase + qf * 16 + li;
          f16x4 hv = *(const f16x4*)(biasb + (size_t)i * 512 + j0);
          f32x4 ci = {(float)hv[0], (float)hv[1], (float)hv[2], (float)hv[3]};
          f32x4 s = __builtin_amdgcn_mfma_f32_16x16x32_bf16(kfr[kfl], qfrag[qf], ci, 0, 0, 0);
          unsigned nib = (unsigned)(mb[qf] >> (kf * 16 + 4 * g)) & 15u;
          float p0 = (nib & 1u) ? __builtin_amdgcn_exp2f(s[0]) : 0.0f;
          float p1 = (nib & 2u) ? __builtin_amdgcn_exp2f(s[1]) : 0.0f;
          float p2 = (nib & 4u) ? __builtin_amdgcn_exp2f(s[2]) : 0.0f;
          float p3 = (nib & 8u) ? __builtin_amdgcn_exp2f(s[3]) : 0.0f;
          l_part[qf] += (p0 + p1) + (p2 + p3);
          lo[qf][kfl] = pack2bf(p0, p1);
          hi[qf][kfl] = pack2bf(p2, p3);
        }
      }
      // In-register P^T relayout: dest lane (g,li) needs keys j32+8g..+7 of
      // q-col li. swap32 then swap16 produce exactly the B-frag words:
      //   {W(e0e1), W(e4e5)} = swap16(swap32(lo0, lo1))
      //   {W(e2e3), W(e6e7)} = swap16(swap32(hi0, hi1))
#pragma unroll
      for (int qf = 0; qf < 2; ++qf) {
        uint2v sl = __builtin_amdgcn_permlane32_swap(lo[qf][0], lo[qf][1], 0, 0);
        uint2v wl = __builtin_amdgcn_permlane16_swap(sl.x, sl.y, 0, 0);
        uint2v sh = __builtin_amdgcn_permlane32_swap(hi[qf][0], hi[qf][1], 0, 0);
        uint2v wh = __builtin_amdgcn_permlane16_swap(sh.x, sh.y, 0, 0);
        bf16x8 pf = frag_from_words(wl.x, wh.x, wl.y, wh.y);
#pragma unroll
        for (int df = 0; df < 2; ++df)
          oacc[qf][df] = __builtin_amdgcn_mfma_f32_16x16x32_bf16(vfr[df], pf, oacc[qf][df], 0, 0, 0);
      }
    }
  }

  // Epilogue: finish row sums across lane-groups, normalize, store f32x4.
#pragma unroll
  for (int qf = 0; qf < 2; ++qf) {
    float l = l_part[qf];
    l += __shfl_xor(l, 16);
    l += __shfl_xor(l, 32);
    float linv = 1.0f / l;
#pragma unroll
    for (int df = 0; df < 2; ++df) {
      float* op = out + ((size_t)bh * 512 + qbase + qf * 16 + li) * 32 + df * 16 + 4 * g;
      f32x4 r = oacc[qf][df] * linv;
      *(f32x4*)op = r;
    }
  }
}

extern "C" void kernel_launch(void* const* d_in, const int* in_sizes, int n_in,
                              void* d_out, int out_size, void* d_ws, size_t ws_size,
                              hipStream_t stream) {
  const float* x    = (const float*)d_in[0];
  const float* mask = (const float*)d_in[1];
  const float* wqkv = (const float*)d_in[2];
  const float* qb   = (const float*)d_in[3];
  const float* vb   = (const float*)d_in[4];
  const float* w1   = (const float*)d_in[5];
  const float* b1   = (const float*)d_in[6];
  const float* w2   = (const float*)d_in[7];
  const float* tbl  = (const float*)d_in[8];
  const int*   ridx = (const int*)d_in[9];
  float* out = (float*)d_out;

  char* ws = (char*)d_ws;
  float*    tab6  = (float*)(ws);                         //    81,920 B
  _Float16* biasH = (_Float16*)(ws + 81920);              // 3,145,728 B
  u64*      bits  = (u64*)(ws + 81920 + 3145728);         // 2,097,152 B
  __bf16*   wbf   = (__bf16*)(ws + 81920 + 3145728 + 2097152);  // pad 262,144
  __bf16*   Q     = (__bf16*)(ws + 81920 + 3145728 + 2097152 + 262144);
  __bf16*   K     = Q + (size_t)64 * 6 * 512 * 32;        // 12,582,912 B each
  __bf16*   Vt    = K + (size_t)64 * 6 * 512 * 32;
  // total ws use: ~43.3 MB

  wconv_kernel<<<108, 256, 0, stream>>>(wqkv, wbf);
  cpb_kernel<<<14, 256, 0, stream>>>(tbl, w1, b1, w2, tab6);
  bias_expand_kernel<<<1024, 256, 0, stream>>>(ridx, tab6, biasH);
  maskbits_kernel<<<8192, 256, 0, stream>>>(mask, bits);
  qkv_kernel<<<1024, 192, 0, stream>>>(x, wbf, qb, vb, Q, K, Vt);
  attn_kernel<<<1536, 256, 0, stream>>>(bits, biasH, Q, K, Vt, out);
}

// Round 4
// 168.602 us; speedup vs baseline: 1.4644x; 1.1886x over previous
//
#include <hip/hip_runtime.h>
#include <hip/hip_bf16.h>

// WindowAttention3D: B=64 windows, N=512 tokens, H=6 heads, D=32, C=192.
// 3 launches:
//   prep_kernel: wconv (w_qkv->bf16) || cpb MLP (one block/point, reduced
//                via shfl+LDS) || maskbits (mask -> unmasked-bit words)
//   mid_kernel:  qkv bf16-MFMA GEMM (blocks 0..1023) || bias_expand
//                (gather tab6 via rel_pos_index -> fp16, blocks 1024..)
//   attn_kernel: swapped QK^T (mfma(K,Q)); ALL per-iteration loads batched
//                at loop top for 18-deep MLP; P relayout in-register via
//                permlane32/16_swap (no LDS); exp2 no-max softmax; bit-mask.

typedef __bf16 bf16x8 __attribute__((ext_vector_type(8)));
typedef __bf16 bf16x4v __attribute__((ext_vector_type(4)));
typedef float  f32x4  __attribute__((ext_vector_type(4)));
typedef _Float16 f16x4 __attribute__((ext_vector_type(4)));
typedef unsigned uint2v __attribute__((ext_vector_type(2)));
typedef unsigned long long u64;

#define LOG2E 1.4426950408889634f

__device__ __forceinline__ bf16x8 cvt2_bf16x8(f32x4 a, f32x4 b) {
  bf16x8 r;
  r[0] = (__bf16)a[0]; r[1] = (__bf16)a[1]; r[2] = (__bf16)a[2]; r[3] = (__bf16)a[3];
  r[4] = (__bf16)b[0]; r[5] = (__bf16)b[1]; r[6] = (__bf16)b[2]; r[7] = (__bf16)b[3];
  return r;
}

__device__ __forceinline__ unsigned pack2bf(float a, float b) {
  unsigned short ua = __builtin_bit_cast(unsigned short, (__bf16)a);
  unsigned short ub = __builtin_bit_cast(unsigned short, (__bf16)b);
  return (unsigned)ua | ((unsigned)ub << 16);
}

__device__ __forceinline__ bf16x8 frag_from_words(unsigned w0, unsigned w1,
                                                  unsigned w2, unsigned w3) {
  union { unsigned u[4]; bf16x8 v; } f;
  f.u[0] = w0; f.u[1] = w1; f.u[2] = w2; f.u[3] = w3;
  return f.v;
}

// ---------------- k1: fused prep (wconv || cpb || maskbits) -----------------
#define PREP_WCONV 108
#define PREP_CPB   3375
#define PREP_WC    (PREP_WCONV + PREP_CPB)     // 3483
#define PREP_GRID  12288
#define PREP_MB    (PREP_GRID - PREP_WC)       // 8805

__global__ __launch_bounds__(256) void prep_kernel(
    const float* __restrict__ w, __bf16* __restrict__ wbf,
    const float* __restrict__ table, const float* __restrict__ w1,
    const float* __restrict__ b1, const float* __restrict__ w2,
    float* __restrict__ tab6,
    const float* __restrict__ m, u64* __restrict__ bits)
{
  __shared__ float red[4][6];
  int blk = blockIdx.x;
  if (blk < PREP_WCONV) {
    // ---- wconv: 27648 threads x 4 elems
    int t = blk * 256 + threadIdx.x;
    f32x4 v = *(const f32x4*)(w + (size_t)t * 4);
    bf16x4v o;
    o[0] = (__bf16)v[0]; o[1] = (__bf16)v[1]; o[2] = (__bf16)v[2]; o[3] = (__bf16)v[3];
    *(bf16x4v*)(wbf + (size_t)t * 4) = o;
  } else if (blk < PREP_WC) {
    // ---- cpb: one block per table point; 512 hidden units, 2 per thread
    int p = blk - PREP_WCONV;
    float c0 = table[p * 3 + 0], c1 = table[p * 3 + 1], c2 = table[p * 3 + 2];
    float acc[6] = {0.f, 0.f, 0.f, 0.f, 0.f, 0.f};
#pragma unroll
    for (int jj = 0; jj < 2; ++jj) {
      int j = threadIdx.x + jj * 256;
      float hv = w1[j * 3 + 0] * c0 + w1[j * 3 + 1] * c1 + w1[j * 3 + 2] * c2 + b1[j];
      hv = fmaxf(hv, 0.0f);
#pragma unroll
      for (int t = 0; t < 6; ++t) acc[t] += w2[t * 512 + j] * hv;
    }
#pragma unroll
    for (int t = 0; t < 6; ++t) {
      acc[t] += __shfl_xor(acc[t], 1);
      acc[t] += __shfl_xor(acc[t], 2);
      acc[t] += __shfl_xor(acc[t], 4);
      acc[t] += __shfl_xor(acc[t], 8);
      acc[t] += __shfl_xor(acc[t], 16);
      acc[t] += __shfl_xor(acc[t], 32);
    }
    int wave = threadIdx.x >> 6;
    if ((threadIdx.x & 63) == 0)
#pragma unroll
      for (int t = 0; t < 6; ++t) red[wave][t] = acc[t];
    __syncthreads();
    if (threadIdx.x < 6) {
      int t = threadIdx.x;
      float s = red[0][t] + red[1][t] + red[2][t] + red[3][t];
      float sig = 16.0f / (1.0f + expf(-s));
      tab6[p * 6 + t] = sig * LOG2E;    // pre-scale by log2e
    }
  } else {
    // ---- maskbits: bit=1 means unmasked; layout bits[b][jw][i]
    int lane = threadIdx.x & 63;
    for (size_t gid = (size_t)(blk - PREP_WC) * 256 + threadIdx.x;
         gid < 16777216ull; gid += (size_t)PREP_MB * 256) {
      int word = (int)(gid >> 6);
      float v = m[gid];                 // fully coalesced
      u64 bal = __ballot(v == 0.0f);
      if (lane == 0) {
        int b = word >> 12, i = (word >> 3) & 511, jw = word & 7;
        bits[(((size_t)b * 8 + jw) << 9) + i] = bal;
      }
    }
  }
}

// ---------------- k2: fused mid (qkv || bias_expand) ------------------------
// qkv: 1024 blocks x 3 waves; block = 32 tokens, wave = region (0:Q scaled,
// 1:K, 2:V). Q/K epilogue transposes via LDS tile -> 16B coalesced stores.
#define MID_QKV  1024
#define MID_BIAS 1366
#define MID_GRID (MID_QKV + MID_BIAS)

__global__ __launch_bounds__(192) void mid_kernel(
    const float* __restrict__ x,       // (32768,192) fp32
    const __bf16* __restrict__ wbf,    // (576,192) bf16
    const float* __restrict__ qb,      // (192)
    const float* __restrict__ vb,      // (192)
    __bf16* __restrict__ Qo,           // (64*6,512,32)
    __bf16* __restrict__ Ko,           // (64*6,512,32)
    __bf16* __restrict__ Vt,           // (64*6,32,512)
    const int* __restrict__ relidx,    // (512,512)
    const float* __restrict__ tab6,    // (3375,6)
    _Float16* __restrict__ biasH)      // (6,512,512) fp16, pre-scaled LOG2E
{
  __shared__ __bf16 tile[2][32][72];   // waves 0,1 transpose staging (9216 B)
  if (blockIdx.x >= MID_QKV) {
    // ---- bias_expand
    for (int ij = (blockIdx.x - MID_QKV) * 192 + threadIdx.x; ij < 262144;
         ij += MID_BIAS * 192) {
      int idx = relidx[ij];
#pragma unroll
      for (int t = 0; t < 6; ++t)
        biasH[(size_t)t * 262144 + ij] = (_Float16)tab6[idx * 6 + t];
    }
    return;
  }
  // ---- qkv
  const float CQ = 0.17677669529663687f * LOG2E;  // 1/sqrt(32) * log2e
  int lane = threadIdx.x & 63, wave = threadIdx.x >> 6;
  int g = lane >> 4, li = lane & 15;
  int rowbase = blockIdx.x * 32;
  int b = rowbase >> 9, nbase = rowbase & 511;

  bf16x8 a[2][6];
#pragma unroll
  for (int mm = 0; mm < 2; ++mm)
#pragma unroll
    for (int k = 0; k < 6; ++k) {
      const float* xp = x + (size_t)(rowbase + mm * 16 + li) * 192 + k * 32 + 8 * g;
      f32x4 x0 = *(const f32x4*)xp;
      f32x4 x1 = *(const f32x4*)(xp + 4);
      a[mm][k] = cvt2_bf16x8(x0, x1);
    }

  for (int ncl = 0; ncl < 3; ++ncl) {
    int nc = wave * 3 + ncl;           // output col chunk of 64 (region=wave)
    f32x4 acc[2][4];
#pragma unroll
    for (int n = 0; n < 4; ++n) {
      int r = nc * 64 + n * 16 + li;
      float bb = 0.0f;
      if (r < 192) bb = qb[r];
      else if (r >= 384) bb = vb[r - 384];
      f32x4 v = {bb, bb, bb, bb};
      acc[0][n] = v; acc[1][n] = v;
    }
#pragma unroll
    for (int k = 0; k < 6; ++k) {
#pragma unroll
      for (int n = 0; n < 4; ++n) {
        bf16x8 bf = *(const bf16x8*)(wbf + (size_t)(nc * 64 + n * 16 + li) * 192 + k * 32 + 8 * g);
        acc[0][n] = __builtin_amdgcn_mfma_f32_16x16x32_bf16(a[0][k], bf, acc[0][n], 0, 0, 0);
        acc[1][n] = __builtin_amdgcn_mfma_f32_16x16x32_bf16(a[1][k], bf, acc[1][n], 0, 0, 0);
      }
    }
    if (wave < 2) {
      float scale = (wave == 0) ? CQ : 1.0f;
#pragma unroll
      for (int n = 0; n < 4; ++n)
#pragma unroll
        for (int mm = 0; mm < 2; ++mm)
#pragma unroll
          for (int t = 0; t < 4; ++t)
            tile[wave][mm * 16 + 4 * g + t][n * 16 + li] = (__bf16)(acc[mm][n][t] * scale);
    }
    __syncthreads();
    if (wave < 2) {
      int tok = lane & 31, hh = lane >> 5;
      int h = (nc * 2 + hh) % 6;
      __bf16* base = (wave == 0) ? Qo : Ko;
      __bf16* dst = base + ((size_t)(b * 6 + h) * 512 + nbase + tok) * 32;
#pragma unroll
      for (int kq = 0; kq < 4; ++kq)
        *(bf16x8*)(dst + kq * 8) = *(const bf16x8*)&tile[wave][tok][hh * 32 + kq * 8];
    } else {
#pragma unroll
      for (int n = 0; n < 4; ++n) {
        int rr = nc * 64 + n * 16 + li - 384, h = rr >> 5, d = rr & 31;
#pragma unroll
        for (int mm = 0; mm < 2; ++mm) {
          int nn = nbase + mm * 16 + 4 * g;
          bf16x4v pk;
#pragma unroll
          for (int t = 0; t < 4; ++t) pk[t] = (__bf16)acc[mm][n][t];
          *(bf16x4v*)(Vt + ((size_t)(b * 6 + h) * 32 + d) * 512 + nn) = pk;
        }
      }
    }
    __syncthreads();
  }
}

// ---------------- k4: attention (no LDS; batched per-iteration loads) -------
__global__ __launch_bounds__(256) void attn_kernel(
    const u64* __restrict__ bits,      // (64,8,512) unmasked-bit words
    const _Float16* __restrict__ biasH,// (6,512,512) fp16, pre-scaled LOG2E
    const __bf16* __restrict__ Qw,     // (64*6,512,32), pre-scaled
    const __bf16* __restrict__ Kw,     // (64*6,512,32)
    const __bf16* __restrict__ Vt,     // (64*6,32,512)
    float* __restrict__ out)           // (64,6,512,32) fp32
{
  // XCD-chunked bijective swizzle (1536 % 8 == 0)
  int hw = blockIdx.x;
  int wgid = (hw & 7) * 192 + (hw >> 3);
  int qt = wgid & 3, h = (wgid >> 2) % 6, b = wgid / 24;
  int lane = threadIdx.x & 63, wave = threadIdx.x >> 6;
  int g = lane >> 4, li = lane & 15;
  int qbase = qt * 128 + wave * 32;
  int bh = b * 6 + h;

  const __bf16* Qb = Qw + (size_t)bh * 16384;
  const __bf16* Kb = Kw + (size_t)bh * 16384;
  const __bf16* Vb = Vt + (size_t)bh * 16384;
  const _Float16* biasb = biasH + (size_t)h * 262144;
  const u64* bitsb = bits + (size_t)b * 4096;

  bf16x8 qfrag[2];
#pragma unroll
  for (int qf = 0; qf < 2; ++qf)
    qfrag[qf] = *(const bf16x8*)(Qb + (size_t)(qbase + qf * 16 + li) * 32 + 8 * g);

  f32x4 oacc[2][2] = {};        // [qf][df]: O^T frags (col=i, row=d)
  float l_part[2] = {0.f, 0.f};

  for (int kb = 0; kb < 8; ++kb) {      // 64 keys per iteration
    int j64 = kb * 64;
    // ===== batched loads for the whole iteration (18-deep MLP) =====
    u64 mb[2];
#pragma unroll
    for (int qf = 0; qf < 2; ++qf)
      mb[qf] = bitsb[((size_t)kb << 9) + qbase + qf * 16 + li];
    bf16x8 kfr[4];
#pragma unroll
    for (int kf = 0; kf < 4; ++kf)
      kfr[kf] = *(const bf16x8*)(Kb + (size_t)(j64 + kf * 16 + li) * 32 + 8 * g);
    bf16x8 vfr[2][2];
#pragma unroll
    for (int df = 0; df < 2; ++df)
#pragma unroll
      for (int c = 0; c < 2; ++c)
        vfr[df][c] = *(const bf16x8*)(Vb + (size_t)(df * 16 + li) * 512 + j64 + c * 32 + 8 * g);
    f16x4 hv[2][4];               // [qf][kf]
#pragma unroll
    for (int kf = 0; kf < 4; ++kf) {
      int j0 = j64 + kf * 16 + 4 * g;
#pragma unroll
      for (int qf = 0; qf < 2; ++qf)
        hv[qf][kf] = *(const f16x4*)(biasb + (size_t)(qbase + qf * 16 + li) * 512 + j0);
    }
    // ===== compute =====
#pragma unroll
    for (int c = 0; c < 2; ++c) {
      unsigned lo[2][2], hi[2][2];      // [qf][kfl]
#pragma unroll
      for (int kfl = 0; kfl < 2; ++kfl) {
        int kf = c * 2 + kfl;
#pragma unroll
        for (int qf = 0; qf < 2; ++qf) {
          f16x4 hb = hv[qf][kf];
          f32x4 ci = {(float)hb[0], (float)hb[1], (float)hb[2], (float)hb[3]};
          f32x4 s = __builtin_amdgcn_mfma_f32_16x16x32_bf16(kfr[kf], qfrag[qf], ci, 0, 0, 0);
          unsigned nib = (unsigned)(mb[qf] >> (kf * 16 + 4 * g)) & 15u;
          float p0 = (nib & 1u) ? __builtin_amdgcn_exp2f(s[0]) : 0.0f;
          float p1 = (nib & 2u) ? __builtin_amdgcn_exp2f(s[1]) : 0.0f;
          float p2 = (nib & 4u) ? __builtin_amdgcn_exp2f(s[2]) : 0.0f;
          float p3 = (nib & 8u) ? __builtin_amdgcn_exp2f(s[3]) : 0.0f;
          l_part[qf] += (p0 + p1) + (p2 + p3);
          lo[qf][kfl] = pack2bf(p0, p1);
          hi[qf][kfl] = pack2bf(p2, p3);
        }
      }
      // In-register P^T relayout via permlane32_swap + permlane16_swap:
      //   {W(e0e1), W(e4e5)} = swap16(swap32(lo0, lo1))
      //   {W(e2e3), W(e6e7)} = swap16(swap32(hi0, hi1))
#pragma unroll
      for (int qf = 0; qf < 2; ++qf) {
        uint2v sl = __builtin_amdgcn_permlane32_swap(lo[qf][0], lo[qf][1], 0, 0);
        uint2v wl = __builtin_amdgcn_permlane16_swap(sl.x, sl.y, 0, 0);
        uint2v sh = __builtin_amdgcn_permlane32_swap(hi[qf][0], hi[qf][1], 0, 0);
        uint2v wh = __builtin_amdgcn_permlane16_swap(sh.x, sh.y, 0, 0);
        bf16x8 pf = frag_from_words(wl.x, wh.x, wl.y, wh.y);
#pragma unroll
        for (int df = 0; df < 2; ++df)
          oacc[qf][df] = __builtin_amdgcn_mfma_f32_16x16x32_bf16(vfr[df][c], pf, oacc[qf][df], 0, 0, 0);
      }
    }
  }

  // Epilogue: finish row sums across lane-groups, normalize, store f32x4.
#pragma unroll
  for (int qf = 0; qf < 2; ++qf) {
    float l = l_part[qf];
    l += __shfl_xor(l, 16);
    l += __shfl_xor(l, 32);
    float linv = 1.0f / l;
#pragma unroll
    for (int df = 0; df < 2; ++df) {
      float* op = out + ((size_t)bh * 512 + qbase + qf * 16 + li) * 32 + df * 16 + 4 * g;
      f32x4 r = oacc[qf][df] * linv;
      *(f32x4*)op = r;
    }
  }
}

extern "C" void kernel_launch(void* const* d_in, const int* in_sizes, int n_in,
                              void* d_out, int out_size, void* d_ws, size_t ws_size,
                              hipStream_t stream) {
  const float* x    = (const float*)d_in[0];
  const float* mask = (const float*)d_in[1];
  const float* wqkv = (const float*)d_in[2];
  const float* qb   = (const float*)d_in[3];
  const float* vb   = (const float*)d_in[4];
  const float* w1   = (const float*)d_in[5];
  const float* b1   = (const float*)d_in[6];
  const float* w2   = (const float*)d_in[7];
  const float* tbl  = (const float*)d_in[8];
  const int*   ridx = (const int*)d_in[9];
  float* out = (float*)d_out;

  char* ws = (char*)d_ws;
  float*    tab6  = (float*)(ws);                         //    81,920 B
  _Float16* biasH = (_Float16*)(ws + 81920);              // 3,145,728 B
  u64*      bits  = (u64*)(ws + 81920 + 3145728);         // 2,097,152 B
  __bf16*   wbf   = (__bf16*)(ws + 81920 + 3145728 + 2097152);  // pad 262,144
  __bf16*   Q     = (__bf16*)(ws + 81920 + 3145728 + 2097152 + 262144);
  __bf16*   K     = Q + (size_t)64 * 6 * 512 * 32;        // 12,582,912 B each
  __bf16*   Vt    = K + (size_t)64 * 6 * 512 * 32;
  // total ws use: ~43.3 MB

  prep_kernel<<<PREP_GRID, 256, 0, stream>>>(wqkv, wbf, tbl, w1, b1, w2, tab6,
                                             mask, bits);
  mid_kernel<<<MID_GRID, 192, 0, stream>>>(x, wbf, qb, vb, Q, K, Vt,
                                           ridx, tab6, biasH);
  attn_kernel<<<1536, 256, 0, stream>>>(bits, biasH, Q, K, Vt, out);
}

// Round 5
// 141.245 us; speedup vs baseline: 1.7480x; 1.1937x over previous
//
#include <hip/hip_runtime.h>
#include <hip/hip_bf16.h>

// WindowAttention3D: B=64 windows, N=512 tokens, H=6 heads, D=32, C=192.
// 3 launches:
//   prep_kernel: wconv (w_qkv->bf16) || cpb MLP (one block/point, reduced
//                via shfl+LDS) || maskbits (mask -> unmasked-bit words)
//   mid_kernel:  qkv bf16-MFMA GEMM (blocks 0..1023) || bias_expand
//                (no __syncthreads: LDS transpose tile is per-wave private)
//   attn_kernel: 64 q-rows/wave (4 q-frags), swapped QK^T (mfma(K,Q));
//                P relayout in-register via permlane32/16_swap (no LDS);
//                exp2 no-max softmax; bit-mask with pre-shifted nibbles.

typedef __bf16 bf16x8 __attribute__((ext_vector_type(8)));
typedef __bf16 bf16x4v __attribute__((ext_vector_type(4)));
typedef float  f32x4  __attribute__((ext_vector_type(4)));
typedef _Float16 f16x4 __attribute__((ext_vector_type(4)));
typedef unsigned uint2v __attribute__((ext_vector_type(2)));
typedef unsigned long long u64;

#define LOG2E 1.4426950408889634f

__device__ __forceinline__ bf16x8 cvt2_bf16x8(f32x4 a, f32x4 b) {
  bf16x8 r;
  r[0] = (__bf16)a[0]; r[1] = (__bf16)a[1]; r[2] = (__bf16)a[2]; r[3] = (__bf16)a[3];
  r[4] = (__bf16)b[0]; r[5] = (__bf16)b[1]; r[6] = (__bf16)b[2]; r[7] = (__bf16)b[3];
  return r;
}

__device__ __forceinline__ unsigned pack2bf(float a, float b) {
  unsigned short ua = __builtin_bit_cast(unsigned short, (__bf16)a);
  unsigned short ub = __builtin_bit_cast(unsigned short, (__bf16)b);
  return (unsigned)ua | ((unsigned)ub << 16);
}

__device__ __forceinline__ bf16x8 frag_from_words(unsigned w0, unsigned w1,
                                                  unsigned w2, unsigned w3) {
  union { unsigned u[4]; bf16x8 v; } f;
  f.u[0] = w0; f.u[1] = w1; f.u[2] = w2; f.u[3] = w3;
  return f.v;
}

// ---------------- k1: fused prep (wconv || cpb || maskbits) -----------------
#define PREP_WCONV 108
#define PREP_CPB   3375
#define PREP_WC    (PREP_WCONV + PREP_CPB)     // 3483
#define PREP_GRID  12288
#define PREP_MB    (PREP_GRID - PREP_WC)       // 8805

__global__ __launch_bounds__(256) void prep_kernel(
    const float* __restrict__ w, __bf16* __restrict__ wbf,
    const float* __restrict__ table, const float* __restrict__ w1,
    const float* __restrict__ b1, const float* __restrict__ w2,
    float* __restrict__ tab6,
    const float* __restrict__ m, u64* __restrict__ bits)
{
  __shared__ float red[4][6];
  int blk = blockIdx.x;
  if (blk < PREP_WCONV) {
    int t = blk * 256 + threadIdx.x;
    f32x4 v = *(const f32x4*)(w + (size_t)t * 4);
    bf16x4v o;
    o[0] = (__bf16)v[0]; o[1] = (__bf16)v[1]; o[2] = (__bf16)v[2]; o[3] = (__bf16)v[3];
    *(bf16x4v*)(wbf + (size_t)t * 4) = o;
  } else if (blk < PREP_WC) {
    int p = blk - PREP_WCONV;
    float c0 = table[p * 3 + 0], c1 = table[p * 3 + 1], c2 = table[p * 3 + 2];
    float acc[6] = {0.f, 0.f, 0.f, 0.f, 0.f, 0.f};
#pragma unroll
    for (int jj = 0; jj < 2; ++jj) {
      int j = threadIdx.x + jj * 256;
      float hv = w1[j * 3 + 0] * c0 + w1[j * 3 + 1] * c1 + w1[j * 3 + 2] * c2 + b1[j];
      hv = fmaxf(hv, 0.0f);
#pragma unroll
      for (int t = 0; t < 6; ++t) acc[t] += w2[t * 512 + j] * hv;
    }
#pragma unroll
    for (int t = 0; t < 6; ++t) {
      acc[t] += __shfl_xor(acc[t], 1);
      acc[t] += __shfl_xor(acc[t], 2);
      acc[t] += __shfl_xor(acc[t], 4);
      acc[t] += __shfl_xor(acc[t], 8);
      acc[t] += __shfl_xor(acc[t], 16);
      acc[t] += __shfl_xor(acc[t], 32);
    }
    int wave = threadIdx.x >> 6;
    if ((threadIdx.x & 63) == 0)
#pragma unroll
      for (int t = 0; t < 6; ++t) red[wave][t] = acc[t];
    __syncthreads();
    if (threadIdx.x < 6) {
      int t = threadIdx.x;
      float s = red[0][t] + red[1][t] + red[2][t] + red[3][t];
      float sig = 16.0f / (1.0f + expf(-s));
      tab6[p * 6 + t] = sig * LOG2E;    // pre-scale by log2e
    }
  } else {
    int lane = threadIdx.x & 63;
    for (size_t gid = (size_t)(blk - PREP_WC) * 256 + threadIdx.x;
         gid < 16777216ull; gid += (size_t)PREP_MB * 256) {
      int word = (int)(gid >> 6);
      float v = m[gid];                 // fully coalesced
      u64 bal = __ballot(v == 0.0f);
      if (lane == 0) {
        int b = word >> 12, i = (word >> 3) & 511, jw = word & 7;
        bits[(((size_t)b * 8 + jw) << 9) + i] = bal;
      }
    }
  }
}

// ---------------- k2: fused mid (qkv || bias_expand) ------------------------
#define MID_QKV  1024
#define MID_BIAS 1366
#define MID_GRID (MID_QKV + MID_BIAS)

__global__ __launch_bounds__(192) void mid_kernel(
    const float* __restrict__ x,       // (32768,192) fp32
    const __bf16* __restrict__ wbf,    // (576,192) bf16
    const float* __restrict__ qb,      // (192)
    const float* __restrict__ vb,      // (192)
    __bf16* __restrict__ Qo,           // (64*6,512,32)
    __bf16* __restrict__ Ko,           // (64*6,512,32)
    __bf16* __restrict__ Vt,           // (64*6,32,512)
    const int* __restrict__ relidx,    // (512,512)
    const float* __restrict__ tab6,    // (3375,6)
    _Float16* __restrict__ biasH)      // (6,512,512) fp16, pre-scaled LOG2E
{
  __shared__ __bf16 tile[2][32][72];   // per-wave private transpose staging
  if (blockIdx.x >= MID_QKV) {
    for (int ij = (blockIdx.x - MID_QKV) * 192 + threadIdx.x; ij < 262144;
         ij += MID_BIAS * 192) {
      int idx = relidx[ij];
#pragma unroll
      for (int t = 0; t < 6; ++t)
        biasH[(size_t)t * 262144 + ij] = (_Float16)tab6[idx * 6 + t];
    }
    return;
  }
  const float CQ = 0.17677669529663687f * LOG2E;  // 1/sqrt(32) * log2e
  int lane = threadIdx.x & 63, wave = threadIdx.x >> 6;
  int g = lane >> 4, li = lane & 15;
  int rowbase = blockIdx.x * 32;
  int b = rowbase >> 9, nbase = rowbase & 511;

  bf16x8 a[2][6];
#pragma unroll
  for (int mm = 0; mm < 2; ++mm)
#pragma unroll
    for (int k = 0; k < 6; ++k) {
      const float* xp = x + (size_t)(rowbase + mm * 16 + li) * 192 + k * 32 + 8 * g;
      f32x4 x0 = *(const f32x4*)xp;
      f32x4 x1 = *(const f32x4*)(xp + 4);
      a[mm][k] = cvt2_bf16x8(x0, x1);
    }

  for (int ncl = 0; ncl < 3; ++ncl) {
    int nc = wave * 3 + ncl;           // output col chunk of 64 (region=wave)
    f32x4 acc[2][4];
#pragma unroll
    for (int n = 0; n < 4; ++n) {
      int r = nc * 64 + n * 16 + li;
      float bb = 0.0f;
      if (r < 192) bb = qb[r];
      else if (r >= 384) bb = vb[r - 384];
      f32x4 v = {bb, bb, bb, bb};
      acc[0][n] = v; acc[1][n] = v;
    }
#pragma unroll
    for (int k = 0; k < 6; ++k) {
#pragma unroll
      for (int n = 0; n < 4; ++n) {
        bf16x8 bf = *(const bf16x8*)(wbf + (size_t)(nc * 64 + n * 16 + li) * 192 + k * 32 + 8 * g);
        acc[0][n] = __builtin_amdgcn_mfma_f32_16x16x32_bf16(a[0][k], bf, acc[0][n], 0, 0, 0);
        acc[1][n] = __builtin_amdgcn_mfma_f32_16x16x32_bf16(a[1][k], bf, acc[1][n], 0, 0, 0);
      }
    }
    // Epilogue. NOTE: tile[wave] is written and read by the SAME wave only —
    // no __syncthreads needed; hardware/compiler waitcnt orders within-wave.
    if (wave < 2) {
      float scale = (wave == 0) ? CQ : 1.0f;
#pragma unroll
      for (int n = 0; n < 4; ++n)
#pragma unroll
        for (int mm = 0; mm < 2; ++mm)
#pragma unroll
          for (int t = 0; t < 4; ++t)
            tile[wave][mm * 16 + 4 * g + t][n * 16 + li] = (__bf16)(acc[mm][n][t] * scale);
      int tok = lane & 31, hh = lane >> 5;
      int h = (nc * 2 + hh) % 6;
      __bf16* base = (wave == 0) ? Qo : Ko;
      __bf16* dst = base + ((size_t)(b * 6 + h) * 512 + nbase + tok) * 32;
#pragma unroll
      for (int kq = 0; kq < 4; ++kq)
        *(bf16x8*)(dst + kq * 8) = *(const bf16x8*)&tile[wave][tok][hh * 32 + kq * 8];
    } else {
#pragma unroll
      for (int n = 0; n < 4; ++n) {
        int rr = nc * 64 + n * 16 + li - 384, h = rr >> 5, d = rr & 31;
#pragma unroll
        for (int mm = 0; mm < 2; ++mm) {
          int nn = nbase + mm * 16 + 4 * g;
          bf16x4v pk;
#pragma unroll
          for (int t = 0; t < 4; ++t) pk[t] = (__bf16)acc[mm][n][t];
          *(bf16x4v*)(Vt + ((size_t)(b * 6 + h) * 32 + d) * 512 + nn) = pk;
        }
      }
    }
  }
}

// ---------------- k4: attention (64 q-rows/wave, no LDS) --------------------
__global__ __launch_bounds__(256, 3) void attn_kernel(
    const u64* __restrict__ bits,      // (64,8,512) unmasked-bit words
    const _Float16* __restrict__ biasH,// (6,512,512) fp16, pre-scaled LOG2E
    const __bf16* __restrict__ Qw,     // (64*6,512,32), pre-scaled
    const __bf16* __restrict__ Kw,     // (64*6,512,32)
    const __bf16* __restrict__ Vt,     // (64*6,32,512)
    float* __restrict__ out)           // (64,6,512,32) fp32
{
  // 768 blocks: XCD-chunked bijective swizzle (768 % 8 == 0, 96/XCD)
  int hw = blockIdx.x;
  int wgid = (hw & 7) * 96 + (hw >> 3);
  int qt = wgid & 1, h = (wgid >> 1) % 6, b = wgid / 12;
  int lane = threadIdx.x & 63, wave = threadIdx.x >> 6;
  int g = lane >> 4, li = lane & 15;
  int qbase = qt * 256 + wave * 64;    // 64 q-rows per wave
  int bh = b * 6 + h;
  int gsh = 4 * g;

  const __bf16* Qb = Qw + (size_t)bh * 16384;
  const __bf16* Kb = Kw + (size_t)bh * 16384;
  const __bf16* Vb = Vt + (size_t)bh * 16384;
  const _Float16* biasb = biasH + (size_t)h * 262144;
  const u64* bitsb = bits + (size_t)b * 4096;

  bf16x8 qfrag[4];
#pragma unroll
  for (int qf = 0; qf < 4; ++qf)
    qfrag[qf] = *(const bf16x8*)(Qb + (qbase + qf * 16 + li) * 32 + 8 * g);

  f32x4 oacc[4][2] = {};        // [qf][df]: O^T frags (col=i, row=d)
  float l_part[4] = {0.f, 0.f, 0.f, 0.f};

  for (int kb = 0; kb < 8; ++kb) {      // 64 keys per iteration
    int j64 = kb * 64;
    u64 mb[4];
#pragma unroll
    for (int qf = 0; qf < 4; ++qf)
      mb[qf] = bitsb[(kb << 9) + qbase + qf * 16 + li] >> gsh;
    bf16x8 kfr[4];
#pragma unroll
    for (int kf = 0; kf < 4; ++kf)
      kfr[kf] = *(const bf16x8*)(Kb + (j64 + kf * 16 + li) * 32 + 8 * g);
    bf16x8 vfr[2][2];
#pragma unroll
    for (int df = 0; df < 2; ++df)
#pragma unroll
      for (int c = 0; c < 2; ++c)
        vfr[df][c] = *(const bf16x8*)(Vb + (df * 16 + li) * 512 + j64 + c * 32 + 8 * g);

#pragma unroll
    for (int c = 0; c < 2; ++c) {
      unsigned lo[4][2], hi[4][2];      // [qf][kfl]
#pragma unroll
      for (int kfl = 0; kfl < 2; ++kfl) {
        int kf = c * 2 + kfl;
        int j0 = j64 + kf * 16 + gsh;   // 4 consecutive keys per lane
#pragma unroll
        for (int qf = 0; qf < 4; ++qf) {
          f16x4 hb = *(const f16x4*)(biasb + (qbase + qf * 16 + li) * 512 + j0);
          f32x4 ci = {(float)hb[0], (float)hb[1], (float)hb[2], (float)hb[3]};
          f32x4 s = __builtin_amdgcn_mfma_f32_16x16x32_bf16(kfr[kf], qfrag[qf], ci, 0, 0, 0);
          unsigned nib = (unsigned)(mb[qf] >> (kf * 16)) & 15u;   // const shift
          float p0 = (nib & 1u) ? __builtin_amdgcn_exp2f(s[0]) : 0.0f;
          float p1 = (nib & 2u) ? __builtin_amdgcn_exp2f(s[1]) : 0.0f;
          float p2 = (nib & 4u) ? __builtin_amdgcn_exp2f(s[2]) : 0.0f;
          float p3 = (nib & 8u) ? __builtin_amdgcn_exp2f(s[3]) : 0.0f;
          l_part[qf] += (p0 + p1) + (p2 + p3);
          lo[qf][kfl] = pack2bf(p0, p1);
          hi[qf][kfl] = pack2bf(p2, p3);
        }
      }
      // In-register P^T relayout via permlane32_swap + permlane16_swap:
      //   {W(e0e1), W(e4e5)} = swap16(swap32(lo0, lo1))
      //   {W(e2e3), W(e6e7)} = swap16(swap32(hi0, hi1))
#pragma unroll
      for (int qf = 0; qf < 4; ++qf) {
        uint2v sl = __builtin_amdgcn_permlane32_swap(lo[qf][0], lo[qf][1], 0, 0);
        uint2v wl = __builtin_amdgcn_permlane16_swap(sl.x, sl.y, 0, 0);
        uint2v sh = __builtin_amdgcn_permlane32_swap(hi[qf][0], hi[qf][1], 0, 0);
        uint2v wh = __builtin_amdgcn_permlane16_swap(sh.x, sh.y, 0, 0);
        bf16x8 pf = frag_from_words(wl.x, wh.x, wl.y, wh.y);
#pragma unroll
        for (int df = 0; df < 2; ++df)
          oacc[qf][df] = __builtin_amdgcn_mfma_f32_16x16x32_bf16(vfr[df][c], pf, oacc[qf][df], 0, 0, 0);
      }
    }
  }

  // Epilogue: finish row sums across lane-groups, normalize, store f32x4.
#pragma unroll
  for (int qf = 0; qf < 4; ++qf) {
    float l = l_part[qf];
    l += __shfl_xor(l, 16);
    l += __shfl_xor(l, 32);
    float linv = 1.0f / l;
#pragma unroll
    for (int df = 0; df < 2; ++df) {
      float* op = out + ((size_t)bh * 512 + qbase + qf * 16 + li) * 32 + df * 16 + 4 * g;
      f32x4 r = oacc[qf][df] * linv;
      *(f32x4*)op = r;
    }
  }
}

extern "C" void kernel_launch(void* const* d_in, const int* in_sizes, int n_in,
                              void* d_out, int out_size, void* d_ws, size_t ws_size,
                              hipStream_t stream) {
  const float* x    = (const float*)d_in[0];
  const float* mask = (const float*)d_in[1];
  const float* wqkv = (const float*)d_in[2];
  const float* qb   = (const float*)d_in[3];
  const float* vb   = (const float*)d_in[4];
  const float* w1   = (const float*)d_in[5];
  const float* b1   = (const float*)d_in[6];
  const float* w2   = (const float*)d_in[7];
  const float* tbl  = (const float*)d_in[8];
  const int*   ridx = (const int*)d_in[9];
  float* out = (float*)d_out;

  char* ws = (char*)d_ws;
  float*    tab6  = (float*)(ws);                         //    81,920 B
  _Float16* biasH = (_Float16*)(ws + 81920);              // 3,145,728 B
  u64*      bits  = (u64*)(ws + 81920 + 3145728);         // 2,097,152 B
  __bf16*   wbf   = (__bf16*)(ws + 81920 + 3145728 + 2097152);  // pad 262,144
  __bf16*   Q     = (__bf16*)(ws + 81920 + 3145728 + 2097152 + 262144);
  __bf16*   K     = Q + (size_t)64 * 6 * 512 * 32;        // 12,582,912 B each
  __bf16*   Vt    = K + (size_t)64 * 6 * 512 * 32;
  // total ws use: ~43.3 MB

  prep_kernel<<<PREP_GRID, 256, 0, stream>>>(wqkv, wbf, tbl, w1, b1, w2, tab6,
                                             mask, bits);
  mid_kernel<<<MID_GRID, 192, 0, stream>>>(x, wbf, qb, vb, Q, K, Vt,
                                           ridx, tab6, biasH);
  attn_kernel<<<768, 256, 0, stream>>>(bits, biasH, Q, K, Vt, out);
}